// Round 1
// baseline (173.597 us; speedup 1.0000x reference)
//
#include <hip/hip_runtime.h>

typedef __attribute__((ext_vector_type(4))) float f32x4;
typedef __attribute__((ext_vector_type(8))) short s16x8;
typedef __attribute__((ext_vector_type(4))) unsigned short u16x4;

__device__ __forceinline__ unsigned short f2bf(float f) {
    union { float f; unsigned int u; } v; v.f = f;
    unsigned int r = v.u + 0x7fffu + ((v.u >> 16) & 1u);
    return (unsigned short)(r >> 16);
}
__device__ __forceinline__ float bf2f(unsigned short h) {
    union { unsigned int u; float f; } v; v.u = ((unsigned int)h) << 16;
    return v.f;
}
// byte offset into a [48][256] bf16 LDS tile, XOR-swizzled (row stride 512B)
__device__ __forceinline__ unsigned int swz(int row, int col) {
    return (unsigned int)(row * 512 + col * 2) ^ (((unsigned int)row & 7u) << 4);
}
// byte offset into a [48][256] f32 LDS tile, XOR-swizzled (row stride 1024B)
__device__ __forceinline__ unsigned int swz32(int row, int col) {
    return (unsigned int)(row * 1024 + col * 4) ^ (((unsigned int)row & 7u) << 4);
}

// Pre-transpose + bf16-cast the 4 weight matrices: wt[m][n][k] = bf16(W_m[k][n])
__global__ void prep_w(const float* __restrict__ wq, const float* __restrict__ wk,
                       const float* __restrict__ wv, const float* __restrict__ wo,
                       unsigned short* __restrict__ wt) {
    int idx = blockIdx.x * 256 + threadIdx.x;   // 0..65535
    int n = idx >> 8, k = idx & 255;
    int src = k * 256 + n, dst = n * 256 + k;
    wt[dst]           = f2bf(wq[src]);
    wt[65536  + dst]  = f2bf(wk[src]);
    wt[131072 + dst]  = f2bf(wv[src]);
    wt[196608 + dst]  = f2bf(wo[src]);
}

__global__ __launch_bounds__(256, 2)
void fused_attn(const float* __restrict__ br0, const float* __restrict__ br1,
                const float* __restrict__ br2, const unsigned short* __restrict__ wt,
                const float* __restrict__ bq, const float* __restrict__ bk,
                const float* __restrict__ bv, const float* __restrict__ bo,
                float* __restrict__ out) {
    extern __shared__ char lds[];
    char* Xs = lds;              // [48][256] bf16 = 24576 B ; later reused for O
    char* Qs = lds + 24576;      // [48][256] bf16
    char* Ks = lds + 49152;      // [48][256] bf16
    char* Ys = lds + 24576;      // [48][256] f32 = 49152 B (reuses Qs+Ks after attention)

    const int t    = threadIdx.x;
    const int wave = t >> 6;         // = head index
    const int lane = t & 63;
    const int g    = lane & 15;
    const int u    = lane >> 4;
    const int bi   = blockIdx.x;
    const int b    = bi >> 8;        // batch
    const int l0   = (bi & 255) << 4; // tile start position (multiple of 16)
    const int nb   = wave * 64;      // this wave's output-column base (head slice)

    // ---------------- phase 1: stage X (fused up-interp), bf16 swizzled ----------------
    {
        const int cc = (t & 63) * 4;
        #pragma unroll
        for (int it = 0; it < 12; ++it) {
            int r = it * 4 + wave;          // 0..47 ; whole wave shares one row (uniform branch)
            int n = r >> 4, p = r & 15;
            int l = l0 + p;
            float4 v;
            if (n == 0) {
                v = *(const float4*)(br0 + (size_t)(b * 4096 + l) * 256 + cc);
            } else {
                const float* src = (n == 1) ? br1 : br2;
                int   Lin   = (n == 1) ? 2048 : 1024;
                float scale = (n == 1) ? 0.5f : 0.25f;
                float sp = (l + 0.5f) * scale - 0.5f;
                sp = fminf(fmaxf(sp, 0.0f), (float)(Lin - 1));
                int i0 = (int)sp;
                int i1 = min(i0 + 1, Lin - 1);
                float w = sp - (float)i0;
                float4 a0 = *(const float4*)(src + (size_t)(b * Lin + i0) * 256 + cc);
                float4 a1 = *(const float4*)(src + (size_t)(b * Lin + i1) * 256 + cc);
                v.x = a0.x * (1.0f - w) + a1.x * w;
                v.y = a0.y * (1.0f - w) + a1.y * w;
                v.z = a0.z * (1.0f - w) + a1.z * w;
                v.w = a0.w * (1.0f - w) + a1.w * w;
            }
            u16x4 h;
            h.x = f2bf(v.x); h.y = f2bf(v.y); h.z = f2bf(v.z); h.w = f2bf(v.w);
            *(u16x4*)(Xs + swz(r, cc)) = h;
        }
    }
    __syncthreads();

    // bias preload (per wave column slice)
    float Bq[4], Bk[4], Bv[4], Bo[4];
    #pragma unroll
    for (int tc = 0; tc < 4; ++tc) {
        int col = nb + tc * 16 + g;
        Bq[tc] = bq[col]; Bk[tc] = bk[col]; Bv[tc] = bv[col]; Bo[tc] = bo[col];
    }

    // per-wave GEMM: [48x256 bf16 LDS] @ [W^T slice] -> acc[3][4] (M=48, N=64, K=256)
    auto gemm = [&](const char* Ab, const unsigned short* w, f32x4 (&acc)[3][4]) {
        #pragma unroll
        for (int rt = 0; rt < 3; ++rt)
            #pragma unroll
            for (int tc = 0; tc < 4; ++tc)
                acc[rt][tc] = (f32x4){0.f, 0.f, 0.f, 0.f};
        for (int k0 = 0; k0 < 256; k0 += 32) {
            s16x8 af[3], bfr[4];
            #pragma unroll
            for (int rt = 0; rt < 3; ++rt)
                af[rt] = *(const s16x8*)(Ab + swz(rt * 16 + g, k0 + u * 8));
            #pragma unroll
            for (int tc = 0; tc < 4; ++tc)
                bfr[tc] = *(const s16x8*)(w + (nb + tc * 16 + g) * 256 + k0 + u * 8);
            #pragma unroll
            for (int rt = 0; rt < 3; ++rt)
                #pragma unroll
                for (int tc = 0; tc < 4; ++tc)
                    acc[rt][tc] = __builtin_amdgcn_mfma_f32_16x16x32_bf16(
                        af[rt], bfr[tc], acc[rt][tc], 0, 0, 0);
        }
    };

    // ---------------- phase 2: projections ----------------
    {
        f32x4 acc[3][4];
        gemm(Xs, wt, acc);                      // Q
        #pragma unroll
        for (int rt = 0; rt < 3; ++rt)
            #pragma unroll
            for (int tc = 0; tc < 4; ++tc)
                #pragma unroll
                for (int j = 0; j < 4; ++j)
                    *(unsigned short*)(Qs + swz(rt * 16 + u * 4 + j, nb + tc * 16 + g)) =
                        f2bf(acc[rt][tc][j] + Bq[tc]);
        gemm(Xs, wt + 65536, acc);              // K
        #pragma unroll
        for (int rt = 0; rt < 3; ++rt)
            #pragma unroll
            for (int tc = 0; tc < 4; ++tc)
                #pragma unroll
                for (int j = 0; j < 4; ++j)
                    *(unsigned short*)(Ks + swz(rt * 16 + u * 4 + j, nb + tc * 16 + g)) =
                        f2bf(acc[rt][tc][j] + Bk[tc]);
    }
    f32x4 vacc[3][4];
    gemm(Xs, wt + 131072, vacc);                // V (kept in registers)
    #pragma unroll
    for (int rt = 0; rt < 3; ++rt)
        #pragma unroll
        for (int tc = 0; tc < 4; ++tc)
            #pragma unroll
            for (int j = 0; j < 4; ++j)
                vacc[rt][tc][j] += Bv[tc];
    __syncthreads();

    // ---------------- phase 3: 3x3 branch attention (per wave = per head) ----------------
    float aw[4][3][3];
    #pragma unroll
    for (int j = 0; j < 4; ++j) {
        int p = u * 4 + j;
        float qf[3][4], kf[3][4];
        #pragma unroll
        for (int n = 0; n < 3; ++n) {
            u16x4 qv = *(const u16x4*)(Qs + swz(n * 16 + p, nb + g * 4));
            u16x4 kv = *(const u16x4*)(Ks + swz(n * 16 + p, nb + g * 4));
            qf[n][0] = bf2f(qv.x); qf[n][1] = bf2f(qv.y); qf[n][2] = bf2f(qv.z); qf[n][3] = bf2f(qv.w);
            kf[n][0] = bf2f(kv.x); kf[n][1] = bf2f(kv.y); kf[n][2] = bf2f(kv.z); kf[n][3] = bf2f(kv.w);
        }
        float s[3][3];
        #pragma unroll
        for (int n = 0; n < 3; ++n)
            #pragma unroll
            for (int m = 0; m < 3; ++m)
                s[n][m] = qf[n][0] * kf[m][0] + qf[n][1] * kf[m][1] +
                          qf[n][2] * kf[m][2] + qf[n][3] * kf[m][3];
        #pragma unroll
        for (int mask = 1; mask < 16; mask <<= 1)
            #pragma unroll
            for (int n = 0; n < 3; ++n)
                #pragma unroll
                for (int m = 0; m < 3; ++m)
                    s[n][m] += __shfl_xor(s[n][m], mask, 16);
        #pragma unroll
        for (int n = 0; n < 3; ++n) {
            float s0 = s[n][0] * 0.125f, s1 = s[n][1] * 0.125f, s2 = s[n][2] * 0.125f;
            float mx = fmaxf(s0, fmaxf(s1, s2));
            float e0 = __expf(s0 - mx), e1 = __expf(s1 - mx), e2 = __expf(s2 - mx);
            float inv = 1.0f / (e0 + e1 + e2);
            aw[j][n][0] = e0 * inv; aw[j][n][1] = e1 * inv; aw[j][n][2] = e2 * inv;
        }
    }
    // O = A @ V (pure per-lane FMA on V fragments), write bf16 into Xs (reused)
    #pragma unroll
    for (int n = 0; n < 3; ++n)
        #pragma unroll
        for (int tc = 0; tc < 4; ++tc)
            #pragma unroll
            for (int j = 0; j < 4; ++j) {
                float o = aw[j][n][0] * vacc[0][tc][j] +
                          aw[j][n][1] * vacc[1][tc][j] +
                          aw[j][n][2] * vacc[2][tc][j];
                *(unsigned short*)(Xs + swz(n * 16 + u * 4 + j, nb + tc * 16 + g)) = f2bf(o);
            }
    __syncthreads();   // all Qs/Ks reads done; O complete in Xs

    // ---------------- phase 4: output projection ----------------
    f32x4 yacc[3][4];
    gemm(Xs, wt + 196608, yacc);
    #pragma unroll
    for (int rt = 0; rt < 3; ++rt)
        #pragma unroll
        for (int tc = 0; tc < 4; ++tc)
            #pragma unroll
            for (int j = 0; j < 4; ++j)
                *(float*)(Ys + swz32(rt * 16 + u * 4 + j, nb + tc * 16 + g)) =
                    yacc[rt][tc][j] + Bo[tc];
    __syncthreads();

    // ---------------- phase 5: epilogue (fused down-interp, coalesced fp32 stores) -------
    {   // branch0: identity, rows 0..15
        int p = t >> 4;
        int c = (t & 15) * 16;
        float* dst = out + (size_t)(b * 4096 + l0 + p) * 256 + c;
        #pragma unroll
        for (int q4 = 0; q4 < 4; ++q4)
            *(f32x4*)(dst + q4 * 4) = *(const f32x4*)(Ys + swz32(p, c + q4 * 4));
    }
    {   // branch1: out1[l'] = 0.5*(y1[2l'] + y1[2l'+1]), rows 16..31
        int q = t >> 5;
        int c = (t & 31) * 8;
        float* dst = out + 8388608 + (size_t)(b * 2048 + (l0 >> 1) + q) * 256 + c;
        #pragma unroll
        for (int q4 = 0; q4 < 2; ++q4) {
            f32x4 v0 = *(const f32x4*)(Ys + swz32(16 + 2 * q,     c + q4 * 4));
            f32x4 v1 = *(const f32x4*)(Ys + swz32(16 + 2 * q + 1, c + q4 * 4));
            *(f32x4*)(dst + q4 * 4) = (v0 + v1) * 0.5f;
        }
    }
    {   // branch2: out2[l''] = 0.5*(y2[4l''+1] + y2[4l''+2]), rows 32..47
        int s2 = t >> 6;
        int c = (t & 63) * 4;
        float* dst = out + 12582912 + (size_t)(b * 1024 + (l0 >> 2) + s2) * 256 + c;
        f32x4 v0 = *(const f32x4*)(Ys + swz32(32 + 4 * s2 + 1, c));
        f32x4 v1 = *(const f32x4*)(Ys + swz32(32 + 4 * s2 + 2, c));
        *(f32x4*)dst = (v0 + v1) * 0.5f;
    }
}

extern "C" void kernel_launch(void* const* d_in, const int* in_sizes, int n_in,
                              void* d_out, int out_size, void* d_ws, size_t ws_size,
                              hipStream_t stream) {
    const float* br0 = (const float*)d_in[0];
    const float* br1 = (const float*)d_in[1];
    const float* br2 = (const float*)d_in[2];
    const float* Wq  = (const float*)d_in[3];
    const float* bq  = (const float*)d_in[4];
    const float* Wk  = (const float*)d_in[5];
    const float* bk  = (const float*)d_in[6];
    const float* Wv  = (const float*)d_in[7];
    const float* bv  = (const float*)d_in[8];
    const float* Wo  = (const float*)d_in[9];
    const float* bo  = (const float*)d_in[10];

    unsigned short* wt = (unsigned short*)d_ws;   // 4 * 256*256 bf16 = 512 KB

    prep_w<<<256, 256, 0, stream>>>(Wq, Wk, Wv, Wo, wt);
    fused_attn<<<2048, 256, 73728, stream>>>(br0, br1, br2, wt, bq, bk, bv, bo,
                                             (float*)d_out);
}